// Round 3
// baseline (2234.250 us; speedup 1.0000x reference)
//
#include <hip/hip_runtime.h>
#include <hip/hip_bf16.h>
#include <math.h>

// Problem constants: S=512, B=256, V=100000, E=128, H=256
#define S_LEN 512
#define B_SZ  256
#define E_SZ  128
#define H_SZ  256

#define HPAD  264                   // 16B-aligned row stride; 2-way bank alias (free)
#define NSCAN 16                    // scan blocks (16 batch rows each)
#define NPROJ (S_LEN * B_SZ / 16)   // 8192 proj blocks (16 xproj rows each)

typedef __attribute__((ext_vector_type(8))) short bf16x8;
typedef __attribute__((ext_vector_type(4))) float f32x4;

__device__ __forceinline__ short f2bf(float f) {
    union { float f; unsigned u; } v; v.f = f;
    unsigned r = v.u + 0x7FFFu + ((v.u >> 16) & 1u);   // RNE
    return (short)(r >> 16);
}
__device__ __forceinline__ float bf2f(unsigned short u) {
    union { unsigned u; float f; } v; v.u = ((unsigned)u) << 16; return v.f;
}
__device__ __forceinline__ unsigned pk2bf(float a, float b) {
    union { __hip_bfloat162 h; unsigned u; } v;
    v.h = __float22bfloat162_rn(make_float2(a, b));     // v_cvt_pk_bf16_f32
    return v.u;
}
__device__ __forceinline__ float tanh_fast(float v) {
    // tanh(v) = 1 - 2/(exp(2v)+1); exact at +/-inf
    return 1.f - 2.f / (__expf(2.f * v) + 1.f);
}

// ---------------------------------------------------------------------------
// Fused kernel.
//  blocks [NSCAN, NSCAN+NPROJ): producer — MFMA GEMM xproj rows (16 per block)
//     D[m=h][n=row] = W_ih * emb_rows^T (+bias), stored bf16 [row][h];
//     release flag per row-group.
//  blocks [0, NSCAN): consumer — recurrent scan, 16 batch rows per block,
//     4 waves x 4 m-tiles, W_hh in 128 VGPRs, state round-trips LDS in bf16,
//     xp prefetched 2 steps ahead straight into the MFMA accumulator.
// ---------------------------------------------------------------------------
__global__ __launch_bounds__(256) void fused_rnn_kernel(
    const int*   __restrict__ X,
    const float* __restrict__ emb,
    const float* __restrict__ W_ih,
    const float* __restrict__ W_hh,
    const float* __restrict__ b_ih,
    const float* __restrict__ b_hh,
    float*       __restrict__ out,
    unsigned short* __restrict__ xproj,
    int*         __restrict__ flags)
{
    const int tid  = threadIdx.x;
    const int wave = tid >> 6;
    const int lane = tid & 63;
    const int bl   = lane & 15;
    const int quad = lane >> 4;

    __shared__ short Hbuf[2][16][HPAD];
    __shared__ float sred[4][16];

    if (blockIdx.x >= NSCAN) {
        // ================= producer: xproj row-group =================
        const int rg   = blockIdx.x - NSCAN;     // 0..8191, rows rg*16..
        const int row0 = rg * 16;
        const int tok  = X[row0 + bl];           // B-frag n = bl -> row

        // B-frags: gathered embedding rows, bf16. B[k=quad*8+j][n=bl]
        bf16x8 bfr[4];
#pragma unroll
        for (int kk = 0; kk < 4; ++kk) {
            const float* p = emb + (size_t)tok * E_SZ + kk * 32 + quad * 8;
            float4 a = *(const float4*)p, b = *(const float4*)(p + 4);
            bf16x8 f;
            f[0]=f2bf(a.x); f[1]=f2bf(a.y); f[2]=f2bf(a.z); f[3]=f2bf(a.w);
            f[4]=f2bf(b.x); f[5]=f2bf(b.y); f[6]=f2bf(b.z); f[7]=f2bf(b.w);
            bfr[kk] = f;
        }
#pragma unroll
        for (int tt = 0; tt < 4; ++tt) {
            const int tile = wave * 4 + tt;      // h-tile 0..15
            const int hA   = tile * 16 + bl;     // A-frag m = bl -> h
            f32x4 acc = {0.f, 0.f, 0.f, 0.f};
#pragma unroll
            for (int kk = 0; kk < 4; ++kk) {
                const float* p = W_ih + (size_t)hA * E_SZ + kk * 32 + quad * 8;
                float4 a = *(const float4*)p, b = *(const float4*)(p + 4);
                bf16x8 f;
                f[0]=f2bf(a.x); f[1]=f2bf(a.y); f[2]=f2bf(a.z); f[3]=f2bf(a.w);
                f[4]=f2bf(b.x); f[5]=f2bf(b.y); f[6]=f2bf(b.z); f[7]=f2bf(b.w);
                acc = __builtin_amdgcn_mfma_f32_16x16x32_bf16(f, bfr[kk], acc, 0, 0, 0);
            }
            // D: lane holds rows h = tile*16 + quad*4 + r for xproj row (row0+bl)
            const int hb = tile * 16 + quad * 4;
            float4 bi = *(const float4*)(b_ih + hb);
            float4 bh = *(const float4*)(b_hh + hb);
            uint2 pk;
            pk.x = pk2bf(acc[0] + bi.x + bh.x, acc[1] + bi.y + bh.y);
            pk.y = pk2bf(acc[2] + bi.z + bh.z, acc[3] + bi.w + bh.w);
            *(uint2*)&xproj[(size_t)(row0 + bl) * H_SZ + hb] = pk;
        }
        __threadfence();                         // make stores device-visible
        __syncthreads();
        if (tid == 0)
            __hip_atomic_store(&flags[rg], 1, __ATOMIC_RELEASE, __HIP_MEMORY_SCOPE_AGENT);
        return;
    }

    // ================= consumer: recurrent scan =================
    const int g  = blockIdx.x;
    const int B0 = g * 16;

    // W_hh fragments (A-operand, constant): lane holds
    // A[m=(wave*4+mt)*16+bl][k=kk*32+quad*8+j]  -> 128 VGPRs
    bf16x8 wfrag[4][8];
#pragma unroll
    for (int mt = 0; mt < 4; ++mt) {
        const int h = (wave * 4 + mt) * 16 + bl;
#pragma unroll
        for (int kk = 0; kk < 8; ++kk) {
            const float* wp = W_hh + (size_t)h * H_SZ + kk * 32 + quad * 8;
            float4 x0 = *(const float4*)wp, x1 = *(const float4*)(wp + 4);
            bf16x8 f;
            f[0]=f2bf(x0.x); f[1]=f2bf(x0.y); f[2]=f2bf(x0.z); f[3]=f2bf(x0.w);
            f[4]=f2bf(x1.x); f[5]=f2bf(x1.y); f[6]=f2bf(x1.z); f[7]=f2bf(x1.w);
            wfrag[mt][kk] = f;
        }
    }

    // zero initial state (buffer 0)
    for (int i = tid; i < (16 * HPAD) / 2; i += 256)
        ((unsigned*)&Hbuf[0][0][0])[i] = 0u;

    // ---- prime xp ring: steps 0 and 1, plus flag for step 2 ----
    ushort4 xpr[2][4];
#pragma unroll
    for (int s0 = 0; s0 < 2; ++s0) {
        int fv = 1;
        if (lane == 0)
            fv = __hip_atomic_load(&flags[s0 * 16 + g], __ATOMIC_ACQUIRE, __HIP_MEMORY_SCOPE_AGENT);
        fv = __builtin_amdgcn_readfirstlane(fv);
        if (fv == 0) {
            while (__hip_atomic_load(&flags[s0 * 16 + g], __ATOMIC_ACQUIRE, __HIP_MEMORY_SCOPE_AGENT) == 0)
                __builtin_amdgcn_s_sleep(2);
        }
#pragma unroll
        for (int mt = 0; mt < 4; ++mt) {
            const int tile = wave * 4 + mt;
            xpr[s0][mt] = *(const ushort4*)&xproj[(size_t)(s0 * B_SZ + B0 + bl) * H_SZ + tile * 16 + quad * 4];
        }
    }
    int fl2 = 1;
    if (lane == 0)
        fl2 = __hip_atomic_load(&flags[2 * 16 + g], __ATOMIC_ACQUIRE, __HIP_MEMORY_SCOPE_AGENT);
    fl2 = __builtin_amdgcn_readfirstlane(fl2);

    float vf[4][4];
#pragma unroll
    for (int mt = 0; mt < 4; ++mt)
#pragma unroll
        for (int r = 0; r < 4; ++r) vf[mt][r] = 0.f;

    __syncthreads();

    for (int s = 0; s < S_LEN; ++s) {
        const int cur = s & 1, nxt = cur ^ 1;

        // state B-frags from LDS
        bf16x8 bfrag[8];
#pragma unroll
        for (int kk = 0; kk < 8; ++kk)
            bfrag[kk] = *(const bf16x8*)&Hbuf[cur][bl][kk * 32 + quad * 8];

        // accumulators pre-loaded with xp (saves the epilogue add)
        f32x4 acc[4];
#pragma unroll
        for (int mt = 0; mt < 4; ++mt) {
            const ushort4 xp = xpr[cur][mt];
            f32x4 a = {bf2f(xp.x), bf2f(xp.y), bf2f(xp.z), bf2f(xp.w)};
            acc[mt] = a;
        }

        // 32 MFMAs: kk outer / mt inner keeps 4 independent chains in flight
#pragma unroll
        for (int kk = 0; kk < 8; ++kk)
#pragma unroll
            for (int mt = 0; mt < 4; ++mt)
                acc[mt] = __builtin_amdgcn_mfma_f32_16x16x32_bf16(wfrag[mt][kk], bfrag[kk], acc[mt], 0, 0, 0);

        // prefetch xp for step s+2 (flag was checked one step ahead)
        if (s + 2 < S_LEN) {
            if (fl2 == 0) {
                while (__hip_atomic_load(&flags[(s + 2) * 16 + g], __ATOMIC_ACQUIRE, __HIP_MEMORY_SCOPE_AGENT) == 0)
                    __builtin_amdgcn_s_sleep(2);
            }
#pragma unroll
            for (int mt = 0; mt < 4; ++mt) {
                const int tile = wave * 4 + mt;
                xpr[cur][mt] = *(const ushort4*)&xproj[(size_t)((s + 2) * B_SZ + B0 + bl) * H_SZ + tile * 16 + quad * 4];
            }
            int fv = 1;
            if (s + 3 < S_LEN) {
                if (lane == 0)
                    fv = __hip_atomic_load(&flags[(s + 3) * 16 + g], __ATOMIC_ACQUIRE, __HIP_MEMORY_SCOPE_AGENT);
                fv = __builtin_amdgcn_readfirstlane(fv);
            }
            fl2 = fv;
        }

        // epilogue: tanh, pack bf16, write next state
#pragma unroll
        for (int mt = 0; mt < 4; ++mt) {
            float t0 = tanh_fast(acc[mt][0]);
            float t1 = tanh_fast(acc[mt][1]);
            float t2 = tanh_fast(acc[mt][2]);
            float t3 = tanh_fast(acc[mt][3]);
            if (s == S_LEN - 1) {
                vf[mt][0] = t0; vf[mt][1] = t1; vf[mt][2] = t2; vf[mt][3] = t3;
            }
            uint2 pk; pk.x = pk2bf(t0, t1); pk.y = pk2bf(t2, t3);
            const int tile = wave * 4 + mt;
            *(uint2*)&Hbuf[nxt][bl][tile * 16 + quad * 4] = pk;
        }
        __syncthreads();
    }

    // ---- log_softmax over h for each batch row (lane's row = bl) ----
    float m = -1e30f;
#pragma unroll
    for (int mt = 0; mt < 4; ++mt)
#pragma unroll
        for (int r = 0; r < 4; ++r) m = fmaxf(m, vf[mt][r]);
    m = fmaxf(m, __shfl_xor(m, 16));
    m = fmaxf(m, __shfl_xor(m, 32));
    if (lane < 16) sred[wave][bl] = m;
    __syncthreads();
    m = fmaxf(fmaxf(sred[0][bl], sred[1][bl]), fmaxf(sred[2][bl], sred[3][bl]));
    __syncthreads();

    float ss = 0.f;
#pragma unroll
    for (int mt = 0; mt < 4; ++mt)
#pragma unroll
        for (int r = 0; r < 4; ++r) ss += __expf(vf[mt][r] - m);
    ss += __shfl_xor(ss, 16);
    ss += __shfl_xor(ss, 32);
    if (lane < 16) sred[wave][bl] = ss;
    __syncthreads();
    const float tot = sred[0][bl] + sred[1][bl] + sred[2][bl] + sred[3][bl];
    const float lse = m + __logf(tot);

#pragma unroll
    for (int mt = 0; mt < 4; ++mt) {
        float4 o;
        o.x = vf[mt][0] - lse; o.y = vf[mt][1] - lse;
        o.z = vf[mt][2] - lse; o.w = vf[mt][3] - lse;
        *(float4*)&out[(size_t)(B0 + bl) * H_SZ + (wave * 4 + mt) * 16 + quad * 4] = o;
    }
}

// ---------------------------------------------------------------------------
extern "C" void kernel_launch(void* const* d_in, const int* in_sizes, int n_in,
                              void* d_out, int out_size, void* d_ws, size_t ws_size,
                              hipStream_t stream) {
    const int*   X    = (const int*)  d_in[0];
    const float* emb  = (const float*)d_in[1];
    const float* W_ih = (const float*)d_in[2];
    const float* W_hh = (const float*)d_in[3];
    const float* b_ih = (const float*)d_in[4];
    const float* b_hh = (const float*)d_in[5];
    float* out = (float*)d_out;

    unsigned short* xproj = (unsigned short*)d_ws;   // S*B*H bf16 = 67.1 MB
    int* flags = (int*)((char*)d_ws + (size_t)S_LEN * B_SZ * H_SZ * sizeof(unsigned short));

    hipMemsetAsync(flags, 0, NPROJ * sizeof(int), stream);
    fused_rnn_kernel<<<dim3(NSCAN + NPROJ), 256, 0, stream>>>(
        X, emb, W_ih, W_hh, b_ih, b_hh, out, xproj, flags);
}

// Round 4
// 1063.211 us; speedup vs baseline: 2.1014x; 2.1014x over previous
//
#include <hip/hip_runtime.h>
#include <hip/hip_bf16.h>
#include <math.h>

// Problem constants: S=512, B=256, V=100000, E=128, H=256
#define S_LEN 512
#define B_SZ  256
#define E_SZ  128
#define H_SZ  256
#define HPAD  264   // LDS row stride (shorts): 16B-aligned; b128 reads at even-bank floor

typedef __attribute__((ext_vector_type(8))) short bf16x8;
typedef __attribute__((ext_vector_type(4))) float f32x4;

__device__ __forceinline__ short f2bf(float f) {
    union { float f; unsigned u; } v; v.f = f;
    unsigned r = v.u + 0x7FFFu + ((v.u >> 16) & 1u);   // RNE
    return (short)(r >> 16);
}
__device__ __forceinline__ float bf2f(unsigned short u) {
    union { unsigned u; float f; } v; v.u = ((unsigned)u) << 16; return v.f;
}
__device__ __forceinline__ unsigned pk2bf(float a, float b) {
    union { __hip_bfloat162 h; unsigned u; } v;
    v.h = __float22bfloat162_rn(make_float2(a, b));     // v_cvt_pk_bf16_f32
    return v.u;
}
__device__ __forceinline__ float tanh_fast(float v) {
    return 1.f - 2.f / (__expf(2.f * v) + 1.f);         // exact at +/-inf
}
// Barrier that publishes LDS (lgkmcnt(0)) WITHOUT draining vmcnt — keeps the
// global xp prefetch in flight across the step boundary.
__device__ __forceinline__ void barrier_lds_only() {
    asm volatile("s_waitcnt lgkmcnt(0)\n\ts_barrier" ::: "memory");
}

// ---------------------------------------------------------------------------
// Kernel 1: embedding gather + input projection via MFMA, bf16 output.
// 64 rows/block (4 groups of 16). D[m=h][n=row] = W_ih * emb^T + bias.
// W_ih fragments live in 64 VGPRs/lane, reused across the 4 row-groups.
// ---------------------------------------------------------------------------
#define PROJ_RPB 64
__global__ __launch_bounds__(256) void proj_kernel(
    const int*   __restrict__ X,
    const float* __restrict__ emb,
    const float* __restrict__ W_ih,
    const float* __restrict__ b_ih,
    const float* __restrict__ b_hh,
    unsigned short* __restrict__ xproj)
{
    const int tid  = threadIdx.x;
    const int wave = tid >> 6;
    const int lane = tid & 63;
    const int bl   = lane & 15;
    const int quad = lane >> 4;

    // A-fragments of W_ih + fused bias
    bf16x8 wfrag[4][4];
    float4 bias[4];
#pragma unroll
    for (int mt = 0; mt < 4; ++mt) {
        const int tile = wave * 4 + mt;
        const int hA   = tile * 16 + bl;
#pragma unroll
        for (int kk = 0; kk < 4; ++kk) {
            const float* p = W_ih + (size_t)hA * E_SZ + kk * 32 + quad * 8;
            float4 a = *(const float4*)p, b = *(const float4*)(p + 4);
            bf16x8 f;
            f[0]=f2bf(a.x); f[1]=f2bf(a.y); f[2]=f2bf(a.z); f[3]=f2bf(a.w);
            f[4]=f2bf(b.x); f[5]=f2bf(b.y); f[6]=f2bf(b.z); f[7]=f2bf(b.w);
            wfrag[mt][kk] = f;
        }
        const int hb = tile * 16 + quad * 4;
        float4 bi = *(const float4*)(b_ih + hb);
        float4 bh = *(const float4*)(b_hh + hb);
        bias[mt] = make_float4(bi.x + bh.x, bi.y + bh.y, bi.z + bh.z, bi.w + bh.w);
    }

    const int row0 = blockIdx.x * PROJ_RPB;
#pragma unroll
    for (int rg = 0; rg < 4; ++rg) {
        const int r0  = row0 + rg * 16;
        const int tok = X[r0 + bl];              // B-frag n = bl -> row

        bf16x8 bfr[4];                           // B[k=quad*8+j][n=bl]
#pragma unroll
        for (int kk = 0; kk < 4; ++kk) {
            const float* p = emb + (size_t)tok * E_SZ + kk * 32 + quad * 8;
            float4 a = *(const float4*)p, b = *(const float4*)(p + 4);
            bf16x8 f;
            f[0]=f2bf(a.x); f[1]=f2bf(a.y); f[2]=f2bf(a.z); f[3]=f2bf(a.w);
            f[4]=f2bf(b.x); f[5]=f2bf(b.y); f[6]=f2bf(b.z); f[7]=f2bf(b.w);
            bfr[kk] = f;
        }
#pragma unroll
        for (int mt = 0; mt < 4; ++mt) {
            f32x4 acc = {0.f, 0.f, 0.f, 0.f};
#pragma unroll
            for (int kk = 0; kk < 4; ++kk)
                acc = __builtin_amdgcn_mfma_f32_16x16x32_bf16(wfrag[mt][kk], bfr[kk], acc, 0, 0, 0);
            const int hb = (wave * 4 + mt) * 16 + quad * 4;
            uint2 pk;
            pk.x = pk2bf(acc[0] + bias[mt].x, acc[1] + bias[mt].y);
            pk.y = pk2bf(acc[2] + bias[mt].z, acc[3] + bias[mt].w);
            *(uint2*)&xproj[(size_t)(r0 + bl) * H_SZ + hb] = pk;
        }
    }
}

// ---------------------------------------------------------------------------
// Kernel 2: recurrent scan + log_softmax. 16 blocks x 16 batch rows.
// W_hh in 128 VGPRs/lane; state round-trips LDS in bf16; xp prefetched
// 2 steps ahead into a register ring and consumed as MFMA accumulator init;
// per-step barrier publishes LDS only (no vmcnt drain).
// ---------------------------------------------------------------------------
__global__ __launch_bounds__(256, 1) void rnn_scan_kernel(
    const unsigned short* __restrict__ xproj,
    const float* __restrict__ W_hh,
    float*       __restrict__ out)
{
    const int tid  = threadIdx.x;
    const int wave = tid >> 6;
    const int lane = tid & 63;
    const int bl   = lane & 15;
    const int quad = lane >> 4;
    const int g    = blockIdx.x;
    const int B0   = g * 16;

    __shared__ short Hbuf[2][16][HPAD];
    __shared__ float sred[4][16];

    // W_hh A-fragments: lane holds A[m=(wave*4+mt)*16+bl][k=kk*32+quad*8+j]
    bf16x8 wfrag[4][8];
#pragma unroll
    for (int mt = 0; mt < 4; ++mt) {
        const int h = (wave * 4 + mt) * 16 + bl;
#pragma unroll
        for (int kk = 0; kk < 8; ++kk) {
            const float* wp = W_hh + (size_t)h * H_SZ + kk * 32 + quad * 8;
            float4 x0 = *(const float4*)wp, x1 = *(const float4*)(wp + 4);
            bf16x8 f;
            f[0]=f2bf(x0.x); f[1]=f2bf(x0.y); f[2]=f2bf(x0.z); f[3]=f2bf(x0.w);
            f[4]=f2bf(x1.x); f[5]=f2bf(x1.y); f[6]=f2bf(x1.z); f[7]=f2bf(x1.w);
            wfrag[mt][kk] = f;
        }
    }

    // zero initial state (buffer 0)
    for (int i = tid; i < (16 * HPAD) / 2; i += 256)
        ((unsigned*)&Hbuf[0][0][0])[i] = 0u;

    // prime xp ring (steps 0 and 1)
    const unsigned short* xpb = xproj + (size_t)(B0 + bl) * H_SZ;
    ushort4 xpr[2][4];
#pragma unroll
    for (int s0 = 0; s0 < 2; ++s0)
#pragma unroll
        for (int mt = 0; mt < 4; ++mt)
            xpr[s0][mt] = *(const ushort4*)(xpb + (size_t)s0 * B_SZ * H_SZ
                                            + (wave * 4 + mt) * 16 + quad * 4);

    __syncthreads();

    for (int s = 0; s < S_LEN; ++s) {
        const int cur = s & 1, nxt = cur ^ 1;

        // state B-frags from LDS
        bf16x8 bfrag[8];
#pragma unroll
        for (int kk = 0; kk < 8; ++kk)
            bfrag[kk] = *(const bf16x8*)&Hbuf[cur][bl][kk * 32 + quad * 8];

        // accumulators pre-loaded with xp
        f32x4 acc[4];
#pragma unroll
        for (int mt = 0; mt < 4; ++mt) {
            const ushort4 xp = xpr[cur][mt];
            f32x4 a = {bf2f(xp.x), bf2f(xp.y), bf2f(xp.z), bf2f(xp.w)};
            acc[mt] = a;
        }

        // 32 MFMAs: kk outer / mt inner -> 4 independent chains
#pragma unroll
        for (int kk = 0; kk < 8; ++kk)
#pragma unroll
            for (int mt = 0; mt < 4; ++mt)
                acc[mt] = __builtin_amdgcn_mfma_f32_16x16x32_bf16(wfrag[mt][kk], bfrag[kk], acc[mt], 0, 0, 0);

        // prefetch xp for step s+2 (stays in flight across the barrier)
        if (s + 2 < S_LEN) {
            const unsigned short* xpn = xpb + (size_t)(s + 2) * B_SZ * H_SZ;
#pragma unroll
            for (int mt = 0; mt < 4; ++mt)
                xpr[cur][mt] = *(const ushort4*)(xpn + (wave * 4 + mt) * 16 + quad * 4);
        }

        // epilogue: tanh, pack bf16, write next state
#pragma unroll
        for (int mt = 0; mt < 4; ++mt) {
            float t0 = tanh_fast(acc[mt][0]);
            float t1 = tanh_fast(acc[mt][1]);
            float t2 = tanh_fast(acc[mt][2]);
            float t3 = tanh_fast(acc[mt][3]);
            uint2 pk; pk.x = pk2bf(t0, t1); pk.y = pk2bf(t2, t3);
            *(uint2*)&Hbuf[nxt][bl][(wave * 4 + mt) * 16 + quad * 4] = pk;
        }
        barrier_lds_only();   // publish LDS; do NOT drain vmcnt
    }

    // final state is in buffer (S_LEN-1 & 1)^1 == 0; read lane's 16 values
    float vf[4][4];
#pragma unroll
    for (int mt = 0; mt < 4; ++mt) {
        ushort4 hs = *(const ushort4*)&Hbuf[0][bl][(wave * 4 + mt) * 16 + quad * 4];
        vf[mt][0] = bf2f(hs.x); vf[mt][1] = bf2f(hs.y);
        vf[mt][2] = bf2f(hs.z); vf[mt][3] = bf2f(hs.w);
    }

    // ---- log_softmax over h for each batch row (lane's row = bl) ----
    float m = -1e30f;
#pragma unroll
    for (int mt = 0; mt < 4; ++mt)
#pragma unroll
        for (int r = 0; r < 4; ++r) m = fmaxf(m, vf[mt][r]);
    m = fmaxf(m, __shfl_xor(m, 16));
    m = fmaxf(m, __shfl_xor(m, 32));
    if (lane < 16) sred[wave][bl] = m;
    __syncthreads();
    m = fmaxf(fmaxf(sred[0][bl], sred[1][bl]), fmaxf(sred[2][bl], sred[3][bl]));
    __syncthreads();

    float ss = 0.f;
#pragma unroll
    for (int mt = 0; mt < 4; ++mt)
#pragma unroll
        for (int r = 0; r < 4; ++r) ss += __expf(vf[mt][r] - m);
    ss += __shfl_xor(ss, 16);
    ss += __shfl_xor(ss, 32);
    if (lane < 16) sred[wave][bl] = ss;
    __syncthreads();
    const float tot = sred[0][bl] + sred[1][bl] + sred[2][bl] + sred[3][bl];
    const float lse = m + __logf(tot);

#pragma unroll
    for (int mt = 0; mt < 4; ++mt) {
        float4 o;
        o.x = vf[mt][0] - lse; o.y = vf[mt][1] - lse;
        o.z = vf[mt][2] - lse; o.w = vf[mt][3] - lse;
        *(float4*)&out[(size_t)(B0 + bl) * H_SZ + (wave * 4 + mt) * 16 + quad * 4] = o;
    }
}

// ---------------------------------------------------------------------------
extern "C" void kernel_launch(void* const* d_in, const int* in_sizes, int n_in,
                              void* d_out, int out_size, void* d_ws, size_t ws_size,
                              hipStream_t stream) {
    const int*   X    = (const int*)  d_in[0];
    const float* emb  = (const float*)d_in[1];
    const float* W_ih = (const float*)d_in[2];
    const float* W_hh = (const float*)d_in[3];
    const float* b_ih = (const float*)d_in[4];
    const float* b_hh = (const float*)d_in[5];
    float* out = (float*)d_out;

    unsigned short* xproj = (unsigned short*)d_ws;   // S*B*H bf16 = 67.1 MB

    proj_kernel<<<dim3(S_LEN * B_SZ / PROJ_RPB), 256, 0, stream>>>(
        X, emb, W_ih, b_ih, b_hh, xproj);

    rnn_scan_kernel<<<dim3(B_SZ / 16), 256, 0, stream>>>(xproj, W_hh, out);
}

// Round 5
// 800.009 us; speedup vs baseline: 2.7928x; 1.3290x over previous
//
#include <hip/hip_runtime.h>
#include <hip/hip_bf16.h>
#include <math.h>

// Problem constants: S=512, B=256, V=100000, E=128, H=256
#define S_LEN 512
#define B_SZ  256
#define E_SZ  128
#define H_SZ  256
#define HPAD  264   // LDS state-row stride in shorts (16B-aligned, bank-spread)

typedef __attribute__((ext_vector_type(8))) short bf16x8;
typedef __attribute__((ext_vector_type(4))) float f32x4;

__device__ __forceinline__ short f2bf(float f) {
    union { float f; unsigned u; } v; v.f = f;
    unsigned r = v.u + 0x7FFFu + ((v.u >> 16) & 1u);   // RNE
    return (short)(r >> 16);
}
__device__ __forceinline__ float bf2f(unsigned short u) {
    union { unsigned u; float f; } v; v.u = ((unsigned)u) << 16; return v.f;
}
__device__ __forceinline__ unsigned pk2bf(float a, float b) {
    union { __hip_bfloat162 h; unsigned u; } v;
    v.h = __float22bfloat162_rn(make_float2(a, b));     // v_cvt_pk_bf16_f32
    return v.u;
}
__device__ __forceinline__ float tanh_fast(float v) {
    return 1.f - 2.f / (__expf(2.f * v) + 1.f);         // exact at +/-inf
}
// Workgroup barrier that publishes LDS only (s_waitcnt lgkmcnt(0) + s_barrier)
// WITHOUT draining vmcnt — keeps global prefetches in flight across steps.
// Uses the address-space-qualified fence so the scheduler models it properly.
__device__ __forceinline__ void barrier_lds() {
    __builtin_amdgcn_fence(__ATOMIC_RELEASE, "workgroup", "local");
    __builtin_amdgcn_s_barrier();
    __builtin_amdgcn_fence(__ATOMIC_ACQUIRE, "workgroup", "local");
}

// ---------------------------------------------------------------------------
// Kernel 1: embedding gather + input projection via MFMA, bf16 output.
// 64 rows/block (4 groups of 16). D[m=h][n=row] = W_ih * emb^T + bias.
// D-fragments go through an LDS slab so global stores are coalesced 16B/lane.
// ---------------------------------------------------------------------------
#define PROJ_RPB 64
__global__ __launch_bounds__(256) void proj_kernel(
    const int*   __restrict__ X,
    const float* __restrict__ emb,
    const float* __restrict__ W_ih,
    const float* __restrict__ b_ih,
    const float* __restrict__ b_hh,
    unsigned short* __restrict__ xproj)
{
    const int tid  = threadIdx.x;
    const int wave = tid >> 6;
    const int lane = tid & 63;
    const int bl   = lane & 15;
    const int quad = lane >> 4;

    __shared__ short slab[16][HPAD];

    // A-fragments of W_ih + fused bias (persist across the 4 row-groups)
    bf16x8 wfrag[4][4];
    float4 bias[4];
#pragma unroll
    for (int mt = 0; mt < 4; ++mt) {
        const int tile = wave * 4 + mt;
        const int hA   = tile * 16 + bl;
#pragma unroll
        for (int kk = 0; kk < 4; ++kk) {
            const float* p = W_ih + (size_t)hA * E_SZ + kk * 32 + quad * 8;
            float4 a = *(const float4*)p, b = *(const float4*)(p + 4);
            bf16x8 f;
            f[0]=f2bf(a.x); f[1]=f2bf(a.y); f[2]=f2bf(a.z); f[3]=f2bf(a.w);
            f[4]=f2bf(b.x); f[5]=f2bf(b.y); f[6]=f2bf(b.z); f[7]=f2bf(b.w);
            wfrag[mt][kk] = f;
        }
        const int hb = tile * 16 + quad * 4;
        float4 bi = *(const float4*)(b_ih + hb);
        float4 bh = *(const float4*)(b_hh + hb);
        bias[mt] = make_float4(bi.x + bh.x, bi.y + bh.y, bi.z + bh.z, bi.w + bh.w);
    }

    const int row0 = blockIdx.x * PROJ_RPB;
#pragma unroll
    for (int rg = 0; rg < 4; ++rg) {
        const int r0  = row0 + rg * 16;
        const int tok = X[r0 + bl];              // B-frag n = bl -> row

        bf16x8 bfr[4];                           // B[k=quad*8+j][n=bl]
#pragma unroll
        for (int kk = 0; kk < 4; ++kk) {
            const float* p = emb + (size_t)tok * E_SZ + kk * 32 + quad * 8;
            float4 a = *(const float4*)p, b = *(const float4*)(p + 4);
            bf16x8 f;
            f[0]=f2bf(a.x); f[1]=f2bf(a.y); f[2]=f2bf(a.z); f[3]=f2bf(a.w);
            f[4]=f2bf(b.x); f[5]=f2bf(b.y); f[6]=f2bf(b.z); f[7]=f2bf(b.w);
            bfr[kk] = f;
        }
#pragma unroll
        for (int mt = 0; mt < 4; ++mt) {
            f32x4 acc = {0.f, 0.f, 0.f, 0.f};
#pragma unroll
            for (int kk = 0; kk < 4; ++kk)
                acc = __builtin_amdgcn_mfma_f32_16x16x32_bf16(wfrag[mt][kk], bfr[kk], acc, 0, 0, 0);
            const int hb = (wave * 4 + mt) * 16 + quad * 4;
            uint2 pk;
            pk.x = pk2bf(acc[0] + bias[mt].x, acc[1] + bias[mt].y);
            pk.y = pk2bf(acc[2] + bias[mt].z, acc[3] + bias[mt].w);
            *(uint2*)&slab[bl][hb] = pk;         // 2-way bank alias only (free)
        }
        __syncthreads();
        // coalesced store: thread t covers two 16B chunks of row (t>>4)
        {
            const int row = tid >> 4;
            const int c0  = tid & 15;
#pragma unroll
            for (int j = 0; j < 2; ++j) {
                const int c16 = c0 + j * 16;     // 0..31 chunks of 8 bf16
                uint4 v = *(const uint4*)&slab[row][c16 * 8];
                *(uint4*)&xproj[(size_t)(r0 + row) * H_SZ + c16 * 8] = v;
            }
        }
        __syncthreads();
    }
}

// ---------------------------------------------------------------------------
// Kernel 2: recurrent scan + log_softmax. 16 blocks x 16 batch rows.
// W_hh in 128 VGPRs/lane; state round-trips LDS in bf16. Loop unrolled x4:
// xp register ring has compile-time slots; prefetch distance 4 steps; the
// per-step barrier publishes LDS only, so prefetches never hit a vmcnt drain.
// ---------------------------------------------------------------------------
__global__ __launch_bounds__(256, 1) void rnn_scan_kernel(
    const unsigned short* __restrict__ xproj,
    const float* __restrict__ W_hh,
    float*       __restrict__ out)
{
    const int tid  = threadIdx.x;
    const int wave = tid >> 6;
    const int lane = tid & 63;
    const int bl   = lane & 15;
    const int quad = lane >> 4;
    const int g    = blockIdx.x;
    const int B0   = g * 16;

    __shared__ short Hbuf[2][16][HPAD];
    __shared__ float sred[4][16];

    // W_hh A-fragments: lane holds A[m=(wave*4+mt)*16+bl][k=kk*32+quad*8+j]
    bf16x8 wfrag[4][8];
#pragma unroll
    for (int mt = 0; mt < 4; ++mt) {
        const int h = (wave * 4 + mt) * 16 + bl;
#pragma unroll
        for (int kk = 0; kk < 8; ++kk) {
            const float* wp = W_hh + (size_t)h * H_SZ + kk * 32 + quad * 8;
            float4 x0 = *(const float4*)wp, x1 = *(const float4*)(wp + 4);
            bf16x8 f;
            f[0]=f2bf(x0.x); f[1]=f2bf(x0.y); f[2]=f2bf(x0.z); f[3]=f2bf(x0.w);
            f[4]=f2bf(x1.x); f[5]=f2bf(x1.y); f[6]=f2bf(x1.z); f[7]=f2bf(x1.w);
            wfrag[mt][kk] = f;
        }
    }

    // zero initial state (buffer 0)
    for (int i = tid; i < (16 * HPAD) / 2; i += 256)
        ((unsigned*)&Hbuf[0][0][0])[i] = 0u;

    // prime xp ring: steps 0..3 (slot j <- step j)
    const unsigned short* xpb = xproj + (size_t)(B0 + bl) * H_SZ;
    ushort4 xpr[4][4];
#pragma unroll
    for (int j = 0; j < 4; ++j)
#pragma unroll
        for (int mt = 0; mt < 4; ++mt)
            xpr[j][mt] = *(const ushort4*)(xpb + (size_t)j * B_SZ * H_SZ
                                           + (wave * 4 + mt) * 16 + quad * 4);

    __syncthreads();

    for (int c = 0; c < S_LEN / 4; ++c) {
#pragma unroll
        for (int j = 0; j < 4; ++j) {
            const int cur = j & 1, nxt = cur ^ 1;

            // state B-frags from LDS
            bf16x8 bfrag[8];
#pragma unroll
            for (int kk = 0; kk < 8; ++kk)
                bfrag[kk] = *(const bf16x8*)&Hbuf[cur][bl][kk * 32 + quad * 8];

            // accumulators pre-loaded with xp (slot j)
            f32x4 acc[4];
#pragma unroll
            for (int mt = 0; mt < 4; ++mt) {
                const ushort4 xp = xpr[j][mt];
                f32x4 a = {bf2f(xp.x), bf2f(xp.y), bf2f(xp.z), bf2f(xp.w)};
                acc[mt] = a;
            }

            // prefetch xp for step c*4+j+4 into the just-freed slot j
            {
                const int sp = c * 4 + j + 4;
                if (sp < S_LEN) {
                    const unsigned short* xpn = xpb + (size_t)sp * B_SZ * H_SZ;
#pragma unroll
                    for (int mt = 0; mt < 4; ++mt)
                        xpr[j][mt] = *(const ushort4*)(xpn + (wave * 4 + mt) * 16 + quad * 4);
                }
            }

            // 32 MFMAs: kk outer / mt inner -> 4 independent chains
#pragma unroll
            for (int kk = 0; kk < 8; ++kk)
#pragma unroll
                for (int mt = 0; mt < 4; ++mt)
                    acc[mt] = __builtin_amdgcn_mfma_f32_16x16x32_bf16(wfrag[mt][kk], bfrag[kk], acc[mt], 0, 0, 0);

            // epilogue: tanh, pack bf16, write next state
#pragma unroll
            for (int mt = 0; mt < 4; ++mt) {
                float t0 = tanh_fast(acc[mt][0]);
                float t1 = tanh_fast(acc[mt][1]);
                float t2 = tanh_fast(acc[mt][2]);
                float t3 = tanh_fast(acc[mt][3]);
                uint2 pk; pk.x = pk2bf(t0, t1); pk.y = pk2bf(t2, t3);
                *(uint2*)&Hbuf[nxt][bl][(wave * 4 + mt) * 16 + quad * 4] = pk;
            }
            barrier_lds();   // lgkmcnt(0)+s_barrier only; vmcnt stays in flight
        }
    }

    // final state is in buffer 0 (step 511 wrote nxt=0); read lane's 16 values
    float vf[4][4];
#pragma unroll
    for (int mt = 0; mt < 4; ++mt) {
        ushort4 hs = *(const ushort4*)&Hbuf[0][bl][(wave * 4 + mt) * 16 + quad * 4];
        vf[mt][0] = bf2f(hs.x); vf[mt][1] = bf2f(hs.y);
        vf[mt][2] = bf2f(hs.z); vf[mt][3] = bf2f(hs.w);
    }

    // ---- log_softmax over h for each batch row (lane's row = bl) ----
    float m = -1e30f;
#pragma unroll
    for (int mt = 0; mt < 4; ++mt)
#pragma unroll
        for (int r = 0; r < 4; ++r) m = fmaxf(m, vf[mt][r]);
    m = fmaxf(m, __shfl_xor(m, 16));
    m = fmaxf(m, __shfl_xor(m, 32));
    if (lane < 16) sred[wave][bl] = m;
    __syncthreads();
    m = fmaxf(fmaxf(sred[0][bl], sred[1][bl]), fmaxf(sred[2][bl], sred[3][bl]));
    __syncthreads();

    float ss = 0.f;
#pragma unroll
    for (int mt = 0; mt < 4; ++mt)
#pragma unroll
        for (int r = 0; r < 4; ++r) ss += __expf(vf[mt][r] - m);
    ss += __shfl_xor(ss, 16);
    ss += __shfl_xor(ss, 32);
    if (lane < 16) sred[wave][bl] = ss;
    __syncthreads();
    const float tot = sred[0][bl] + sred[1][bl] + sred[2][bl] + sred[3][bl];
    const float lse = m + __logf(tot);

#pragma unroll
    for (int mt = 0; mt < 4; ++mt) {
        float4 o;
        o.x = vf[mt][0] - lse; o.y = vf[mt][1] - lse;
        o.z = vf[mt][2] - lse; o.w = vf[mt][3] - lse;
        *(float4*)&out[(size_t)(B0 + bl) * H_SZ + (wave * 4 + mt) * 16 + quad * 4] = o;
    }
}

// ---------------------------------------------------------------------------
extern "C" void kernel_launch(void* const* d_in, const int* in_sizes, int n_in,
                              void* d_out, int out_size, void* d_ws, size_t ws_size,
                              hipStream_t stream) {
    const int*   X    = (const int*)  d_in[0];
    const float* emb  = (const float*)d_in[1];
    const float* W_ih = (const float*)d_in[2];
    const float* W_hh = (const float*)d_in[3];
    const float* b_ih = (const float*)d_in[4];
    const float* b_hh = (const float*)d_in[5];
    float* out = (float*)d_out;

    unsigned short* xproj = (unsigned short*)d_ws;   // S*B*H bf16 = 67.1 MB

    proj_kernel<<<dim3(S_LEN * B_SZ / PROJ_RPB), 256, 0, stream>>>(
        X, emb, W_ih, b_ih, b_hh, xproj);

    rnn_scan_kernel<<<dim3(B_SZ / 16), 256, 0, stream>>>(xproj, W_hh, out);
}

// Round 6
// 715.879 us; speedup vs baseline: 3.1210x; 1.1175x over previous
//
#include <hip/hip_runtime.h>
#include <hip/hip_bf16.h>
#include <math.h>

// Problem constants: S=512, B=256, V=100000, E=128, H=256
#define S_LEN 512
#define B_SZ  256
#define E_SZ  128
#define H_SZ  256
#define HPAD  264   // LDS state-row stride in shorts (16B-aligned)

typedef __attribute__((ext_vector_type(8))) short bf16x8;
typedef __attribute__((ext_vector_type(4))) float f32x4;

__device__ __forceinline__ short f2bf(float f) {
    union { float f; unsigned u; } v; v.f = f;
    unsigned r = v.u + 0x7FFFu + ((v.u >> 16) & 1u);   // RNE
    return (short)(r >> 16);
}
__device__ __forceinline__ float bf2f(unsigned short u) {
    union { unsigned u; float f; } v; v.u = ((unsigned)u) << 16; return v.f;
}
__device__ __forceinline__ unsigned pk2bf(float a, float b) {
    union { __hip_bfloat162 h; unsigned u; } v;
    v.h = __float22bfloat162_rn(make_float2(a, b));     // v_cvt_pk_bf16_f32
    return v.u;
}
__device__ __forceinline__ float tanh_fast(float v) {
    return 1.f - 2.f / (__expf(2.f * v) + 1.f);         // exact at +/-inf
}
// LDS-publishing barrier (lgkmcnt only via addrspace fence) — global
// prefetches stay in flight across steps.
__device__ __forceinline__ void barrier_lds() {
    __builtin_amdgcn_fence(__ATOMIC_RELEASE, "workgroup", "local");
    __builtin_amdgcn_s_barrier();
    __builtin_amdgcn_fence(__ATOMIC_ACQUIRE, "workgroup", "local");
}

// ---------------------------------------------------------------------------
// Kernel 1: embedding gather + input projection via MFMA.
// Output TRANSPOSED: xproj[b][s][h] bf16 — scan lanes then stream their row.
// 128 flat rows/block (8 groups of 16, all same s per block since 128|256).
// ---------------------------------------------------------------------------
#define PROJ_RPB 128
__global__ __launch_bounds__(256) void proj_kernel(
    const int*   __restrict__ X,
    const float* __restrict__ emb,
    const float* __restrict__ W_ih,
    const float* __restrict__ b_ih,
    const float* __restrict__ b_hh,
    unsigned short* __restrict__ xproj)
{
    const int tid  = threadIdx.x;
    const int wave = tid >> 6;
    const int lane = tid & 63;
    const int bl   = lane & 15;
    const int quad = lane >> 4;

    __shared__ short slab[16][HPAD];

    // A-fragments of W_ih + fused bias (persist across row-groups)
    bf16x8 wfrag[4][4];
    float4 bias[4];
#pragma unroll
    for (int mt = 0; mt < 4; ++mt) {
        const int tile = wave * 4 + mt;
        const int hA   = tile * 16 + bl;
#pragma unroll
        for (int kk = 0; kk < 4; ++kk) {
            const float* p = W_ih + (size_t)hA * E_SZ + kk * 32 + quad * 8;
            float4 a = *(const float4*)p, b = *(const float4*)(p + 4);
            bf16x8 f;
            f[0]=f2bf(a.x); f[1]=f2bf(a.y); f[2]=f2bf(a.z); f[3]=f2bf(a.w);
            f[4]=f2bf(b.x); f[5]=f2bf(b.y); f[6]=f2bf(b.z); f[7]=f2bf(b.w);
            wfrag[mt][kk] = f;
        }
        const int hb = tile * 16 + quad * 4;
        float4 bi = *(const float4*)(b_ih + hb);
        float4 bh = *(const float4*)(b_hh + hb);
        bias[mt] = make_float4(bi.x + bh.x, bi.y + bh.y, bi.z + bh.z, bi.w + bh.w);
    }

    const int row0 = blockIdx.x * PROJ_RPB;
#pragma unroll
    for (int rg = 0; rg < PROJ_RPB / 16; ++rg) {
        const int r0  = row0 + rg * 16;
        const int tok = X[r0 + bl];              // flat row = s*B + b

        bf16x8 bfr[4];                           // B[k=quad*8+j][n=bl]
#pragma unroll
        for (int kk = 0; kk < 4; ++kk) {
            const float* p = emb + (size_t)tok * E_SZ + kk * 32 + quad * 8;
            float4 a = *(const float4*)p, b = *(const float4*)(p + 4);
            bf16x8 f;
            f[0]=f2bf(a.x); f[1]=f2bf(a.y); f[2]=f2bf(a.z); f[3]=f2bf(a.w);
            f[4]=f2bf(b.x); f[5]=f2bf(b.y); f[6]=f2bf(b.z); f[7]=f2bf(b.w);
            bfr[kk] = f;
        }
#pragma unroll
        for (int mt = 0; mt < 4; ++mt) {
            f32x4 acc = {0.f, 0.f, 0.f, 0.f};
#pragma unroll
            for (int kk = 0; kk < 4; ++kk)
                acc = __builtin_amdgcn_mfma_f32_16x16x32_bf16(wfrag[mt][kk], bfr[kk], acc, 0, 0, 0);
            const int hb = (wave * 4 + mt) * 16 + quad * 4;
            uint2 pk;
            pk.x = pk2bf(acc[0] + bias[mt].x, acc[1] + bias[mt].y);
            pk.y = pk2bf(acc[2] + bias[mt].z, acc[3] + bias[mt].w);
            *(uint2*)&slab[bl][hb] = pk;
        }
        __syncthreads();
        // store slab rows to transposed xproj[b][s][h]
        {
            const int row  = tid >> 4;           // 0..15
            const int c0   = tid & 15;
            const int flat = r0 + row;
            const int ss   = flat >> 8;          // /B_SZ
            const int bb   = flat & 255;
            unsigned short* dst = xproj + (size_t)bb * S_LEN * H_SZ + (size_t)ss * H_SZ;
#pragma unroll
            for (int j = 0; j < 2; ++j) {
                const int c16 = c0 + j * 16;
                uint4 v = *(const uint4*)&slab[row][c16 * 8];
                *(uint4*)&dst[c16 * 8] = v;
            }
        }
        __syncthreads();
    }
}

// ---------------------------------------------------------------------------
// Kernel 2: recurrent scan + log_softmax. 16 blocks x 16 batch rows,
// 512 threads = 8 waves (2/SIMD -> real TLP). Wave owns 2 m-tiles:
// wfrag 64 VGPRs, no spills. State round-trips LDS in bf16. xp prefetched in
// 4-step chunks, double-buffered, issued ~4 steps before use.
// ---------------------------------------------------------------------------
__global__ __launch_bounds__(512, 2) void rnn_scan_kernel(
    const unsigned short* __restrict__ xproj,   // [B][S][H] bf16
    const float* __restrict__ W_hh,
    float*       __restrict__ out)
{
    const int tid  = threadIdx.x;
    const int wave = tid >> 6;
    const int lane = tid & 63;
    const int bl   = lane & 15;
    const int quad = lane >> 4;
    const int B0   = blockIdx.x * 16;

    __shared__ short Hbuf[2][16][HPAD];

    // W_hh A-fragments: lane holds A[m=(wave*2+mt)*16+bl][k=kk*32+quad*8+j]
    bf16x8 wfrag[2][8];
#pragma unroll
    for (int mt = 0; mt < 2; ++mt) {
        const int h = (wave * 2 + mt) * 16 + bl;
#pragma unroll
        for (int kk = 0; kk < 8; ++kk) {
            const float* wp = W_hh + (size_t)h * H_SZ + kk * 32 + quad * 8;
            float4 x0 = *(const float4*)wp, x1 = *(const float4*)(wp + 4);
            bf16x8 f;
            f[0]=f2bf(x0.x); f[1]=f2bf(x0.y); f[2]=f2bf(x0.z); f[3]=f2bf(x0.w);
            f[4]=f2bf(x1.x); f[5]=f2bf(x1.y); f[6]=f2bf(x1.z); f[7]=f2bf(x1.w);
            wfrag[mt][kk] = f;
        }
    }

    // zero initial state (buffer 0)
    for (int i = tid; i < (16 * HPAD) / 2; i += 512)
        ((unsigned*)&Hbuf[0][0][0])[i] = 0u;

    // lane's xp stream: row (B0+bl), element offset per (step, mt)
    const unsigned short* xpb = xproj + (size_t)(B0 + bl) * S_LEN * H_SZ;
    const int xoff0 = (wave * 2 + 0) * 16 + quad * 4;
    const int xoff1 = (wave * 2 + 1) * 16 + quad * 4;

    ushort4 xpA[4][2], xpB[4][2];
#pragma unroll
    for (int j = 0; j < 4; ++j) {
        xpA[j][0] = *(const ushort4*)(xpb + (size_t)j * H_SZ + xoff0);
        xpA[j][1] = *(const ushort4*)(xpb + (size_t)j * H_SZ + xoff1);
        xpB[j][0] = *(const ushort4*)(xpb + (size_t)(j + 4) * H_SZ + xoff0);
        xpB[j][1] = *(const ushort4*)(xpb + (size_t)(j + 4) * H_SZ + xoff1);
    }

    __syncthreads();

#define SCAN_STEP(CUR, XP0, XP1)                                              \
    do {                                                                      \
        bf16x8 bfrag[8];                                                      \
        _Pragma("unroll")                                                     \
        for (int kk = 0; kk < 8; ++kk)                                        \
            bfrag[kk] = *(const bf16x8*)&Hbuf[CUR][bl][kk * 32 + quad * 8];   \
        f32x4 aE0 = {bf2f((XP0).x), bf2f((XP0).y), bf2f((XP0).z), bf2f((XP0).w)}; \
        f32x4 aE1 = {bf2f((XP1).x), bf2f((XP1).y), bf2f((XP1).z), bf2f((XP1).w)}; \
        f32x4 aO0 = {0.f, 0.f, 0.f, 0.f};                                     \
        f32x4 aO1 = {0.f, 0.f, 0.f, 0.f};                                     \
        _Pragma("unroll")                                                     \
        for (int kp = 0; kp < 4; ++kp) {                                      \
            aE0 = __builtin_amdgcn_mfma_f32_16x16x32_bf16(wfrag[0][2*kp],   bfrag[2*kp],   aE0, 0, 0, 0); \
            aE1 = __builtin_amdgcn_mfma_f32_16x16x32_bf16(wfrag[1][2*kp],   bfrag[2*kp],   aE1, 0, 0, 0); \
            aO0 = __builtin_amdgcn_mfma_f32_16x16x32_bf16(wfrag[0][2*kp+1], bfrag[2*kp+1], aO0, 0, 0, 0); \
            aO1 = __builtin_amdgcn_mfma_f32_16x16x32_bf16(wfrag[1][2*kp+1], bfrag[2*kp+1], aO1, 0, 0, 0); \
        }                                                                     \
        float t0 = tanh_fast(aE0[0] + aO0[0]);                                \
        float t1 = tanh_fast(aE0[1] + aO0[1]);                                \
        float t2 = tanh_fast(aE0[2] + aO0[2]);                                \
        float t3 = tanh_fast(aE0[3] + aO0[3]);                                \
        uint2 pk0; pk0.x = pk2bf(t0, t1); pk0.y = pk2bf(t2, t3);              \
        *(uint2*)&Hbuf[(CUR) ^ 1][bl][(wave * 2 + 0) * 16 + quad * 4] = pk0;  \
        float u0 = tanh_fast(aE1[0] + aO1[0]);                                \
        float u1 = tanh_fast(aE1[1] + aO1[1]);                                \
        float u2 = tanh_fast(aE1[2] + aO1[2]);                                \
        float u3 = tanh_fast(aE1[3] + aO1[3]);                                \
        uint2 pk1; pk1.x = pk2bf(u0, u1); pk1.y = pk2bf(u2, u3);              \
        *(uint2*)&Hbuf[(CUR) ^ 1][bl][(wave * 2 + 1) * 16 + quad * 4] = pk1;  \
        barrier_lds();                                                        \
    } while (0)

    for (int cc = 0; cc < S_LEN / 8; ++cc) {
        const size_t base = (size_t)cc * 8;

        // half-chunk A: steps base..base+3 (parity of step = j&1)
        SCAN_STEP(0, xpA[0][0], xpA[0][1]);
        SCAN_STEP(1, xpA[1][0], xpA[1][1]);
        SCAN_STEP(0, xpA[2][0], xpA[2][1]);
        SCAN_STEP(1, xpA[3][0], xpA[3][1]);

        // xpA free -> prefetch steps base+8..base+11 (used next cc, ~4 steps away)
        if (cc + 1 < S_LEN / 8) {
            const unsigned short* p = xpb + (base + 8) * H_SZ;
#pragma unroll
            for (int j = 0; j < 4; ++j) {
                xpA[j][0] = *(const ushort4*)(p + (size_t)j * H_SZ + xoff0);
                xpA[j][1] = *(const ushort4*)(p + (size_t)j * H_SZ + xoff1);
            }
        }

        // half-chunk B: steps base+4..base+7
        SCAN_STEP(0, xpB[0][0], xpB[0][1]);
        SCAN_STEP(1, xpB[1][0], xpB[1][1]);
        SCAN_STEP(0, xpB[2][0], xpB[2][1]);
        SCAN_STEP(1, xpB[3][0], xpB[3][1]);

        // xpB free -> prefetch steps base+12..base+15
        if (cc + 1 < S_LEN / 8) {
            const unsigned short* p = xpb + (base + 12) * H_SZ;
#pragma unroll
            for (int j = 0; j < 4; ++j) {
                xpB[j][0] = *(const ushort4*)(p + (size_t)j * H_SZ + xoff0);
                xpB[j][1] = *(const ushort4*)(p + (size_t)j * H_SZ + xoff1);
            }
        }
    }
#undef SCAN_STEP

    // final state in Hbuf[0] (step 511 wrote buffer 0)
    __syncthreads();

    // ---- log_softmax: thread t -> batch row t>>5, h chunk (t&31)*8 ----
    {
        const int row = tid >> 5;        // 0..15
        const int j   = tid & 31;        // owns h in [8j, 8j+8)
        float v[8];
        ushort4 h0 = *(const ushort4*)&Hbuf[0][row][j * 8];
        ushort4 h1 = *(const ushort4*)&Hbuf[0][row][j * 8 + 4];
        v[0]=bf2f(h0.x); v[1]=bf2f(h0.y); v[2]=bf2f(h0.z); v[3]=bf2f(h0.w);
        v[4]=bf2f(h1.x); v[5]=bf2f(h1.y); v[6]=bf2f(h1.z); v[7]=bf2f(h1.w);

        float m = v[0];
#pragma unroll
        for (int i = 1; i < 8; ++i) m = fmaxf(m, v[i]);
#pragma unroll
        for (int off = 1; off < 32; off <<= 1) m = fmaxf(m, __shfl_xor(m, off));

        float ss = 0.f;
#pragma unroll
        for (int i = 0; i < 8; ++i) ss += __expf(v[i] - m);
#pragma unroll
        for (int off = 1; off < 32; off <<= 1) ss += __shfl_xor(ss, off);

        const float lse = m + __logf(ss);
        float4 o0 = make_float4(v[0]-lse, v[1]-lse, v[2]-lse, v[3]-lse);
        float4 o1 = make_float4(v[4]-lse, v[5]-lse, v[6]-lse, v[7]-lse);
        float* dst = out + (size_t)(B0 + row) * H_SZ + j * 8;
        *(float4*)dst = o0;
        *(float4*)(dst + 4) = o1;
    }
}

// ---------------------------------------------------------------------------
extern "C" void kernel_launch(void* const* d_in, const int* in_sizes, int n_in,
                              void* d_out, int out_size, void* d_ws, size_t ws_size,
                              hipStream_t stream) {
    const int*   X    = (const int*)  d_in[0];
    const float* emb  = (const float*)d_in[1];
    const float* W_ih = (const float*)d_in[2];
    const float* W_hh = (const float*)d_in[3];
    const float* b_ih = (const float*)d_in[4];
    const float* b_hh = (const float*)d_in[5];
    float* out = (float*)d_out;

    unsigned short* xproj = (unsigned short*)d_ws;   // [B][S][H] bf16 = 67.1 MB

    proj_kernel<<<dim3(S_LEN * B_SZ / PROJ_RPB), 256, 0, stream>>>(
        X, emb, W_ih, b_ih, b_hh, xproj);

    rnn_scan_kernel<<<dim3(B_SZ / 16), 512, 0, stream>>>(xproj, W_hh, out);
}